// Round 3
// baseline (163.849 us; speedup 1.0000x reference)
//
#include <hip/hip_runtime.h>

#define R 4
#define NTHREADS 256

// Setup kernel: fold layers 5+6 (both linear) into w56[12], b56.
// d_ws layout: ws[0..11] = W5@W6, ws[12] = b5@W6 + b6
__global__ void fuse56_kernel(const float* __restrict__ W5, const float* __restrict__ b5,
                              const float* __restrict__ W6, const float* __restrict__ b6,
                              float* __restrict__ ws) {
    const int t = threadIdx.x;
    if (t < 12) {
        float acc = 0.0f;
        #pragma unroll
        for (int c = 0; c < 6; ++c) acc = fmaf(W5[t * 6 + c], W6[c], acc);
        ws[t] = acc;
    } else if (t == 12) {
        float acc = b6[0];
        #pragma unroll
        for (int c = 0; c < 6; ++c) acc = fmaf(b5[c], W6[c], acc);
        ws[12] = acc;
    }
}

// Main kernel: all weight/bias reads are wave-uniform (constant indices off
// uniform __restrict__ pointers) -> scalar s_load path, zero LDS traffic.
// FMAs consume the weight as the SGPR operand: v_fmac_f32 v, s, v.
__global__ __launch_bounds__(NTHREADS, 4) void mlp_kernel(
    const float* __restrict__ in,
    const float* __restrict__ W0, const float* __restrict__ b0,
    const float* __restrict__ W1,
    const float* __restrict__ W2,
    const float* __restrict__ W3,
    const float* __restrict__ W4,
    const float* __restrict__ b1,
    const float* __restrict__ b2,
    const float* __restrict__ b3,
    const float* __restrict__ b4,
    const float* __restrict__ w56,   // d_ws: [0..11] fused weights, [12] fused bias
    float* __restrict__ out, int nrows)
{
    const long t = (long)blockIdx.x * NTHREADS + threadIdx.x;
    const long row0 = t * R;
    if (row0 >= nrows) return;
    const bool full = (row0 + R) <= nrows;

    // ---- load inputs: R*7 = 28 floats = 7 float4 (base 112B-aligned) ----
    float xs[28];
    if (full) {
        const float4* ip = (const float4*)(in + row0 * 7);
        float4 q;
        q = ip[0]; xs[0]=q.x;  xs[1]=q.y;  xs[2]=q.z;  xs[3]=q.w;
        q = ip[1]; xs[4]=q.x;  xs[5]=q.y;  xs[6]=q.z;  xs[7]=q.w;
        q = ip[2]; xs[8]=q.x;  xs[9]=q.y;  xs[10]=q.z; xs[11]=q.w;
        q = ip[3]; xs[12]=q.x; xs[13]=q.y; xs[14]=q.z; xs[15]=q.w;
        q = ip[4]; xs[16]=q.x; xs[17]=q.y; xs[18]=q.z; xs[19]=q.w;
        q = ip[5]; xs[20]=q.x; xs[21]=q.y; xs[22]=q.z; xs[23]=q.w;
        q = ip[6]; xs[24]=q.x; xs[25]=q.y; xs[26]=q.z; xs[27]=q.w;
    } else {
        #pragma unroll
        for (int r = 0; r < R; ++r)
            #pragma unroll
            for (int i = 0; i < 7; ++i)
                xs[r * 7 + i] = ((row0 + r) < nrows) ? in[(row0 + r) * 7 + i] : 0.0f;
    }

    float h[R][12];

    // ---- layer 0: 7 -> 12, linear (i=0 peeled to fold bias) ----
    {
        #pragma unroll
        for (int j = 0; j < 12; ++j) {
            const float wv = W0[j];          // row 0
            const float bv = b0[j];
            #pragma unroll
            for (int r = 0; r < R; ++r)
                h[r][j] = fmaf(xs[r * 7 + 0], wv, bv);
        }
        #pragma unroll
        for (int i = 1; i < 7; ++i) {
            #pragma unroll
            for (int j = 0; j < 12; ++j) {
                const float wv = W0[i * 12 + j];
                #pragma unroll
                for (int r = 0; r < R; ++r)
                    h[r][j] = fmaf(xs[r * 7 + i], wv, h[r][j]);
            }
        }
    }

    // ---- layers 1..4: 12 -> 12, relu ----
    const float* __restrict__ Ws[4] = {W1, W2, W3, W4};
    const float* __restrict__ Bs[4] = {b1, b2, b3, b4};
    #pragma unroll
    for (int li = 0; li < 4; ++li) {
        const float* __restrict__ Wl = Ws[li];
        const float* __restrict__ Bl = Bs[li];
        float nxt[R][12];
        #pragma unroll
        for (int j = 0; j < 12; ++j) {
            const float wv = Wl[j];          // i=0 row, bias folded
            const float bv = Bl[j];
            #pragma unroll
            for (int r = 0; r < R; ++r)
                nxt[r][j] = fmaf(h[r][0], wv, bv);
        }
        #pragma unroll
        for (int i = 1; i < 12; ++i) {
            #pragma unroll
            for (int j = 0; j < 12; ++j) {
                const float wv = Wl[i * 12 + j];
                #pragma unroll
                for (int r = 0; r < R; ++r)
                    nxt[r][j] = fmaf(h[r][i], wv, nxt[r][j]);
            }
        }
        #pragma unroll
        for (int r = 0; r < R; ++r)
            #pragma unroll
            for (int j = 0; j < 12; ++j)
                h[r][j] = fmaxf(nxt[r][j], 0.0f);
    }

    // ---- fused layers 5+6: 12 -> 1, linear ----
    const float b56 = w56[12];
    float o[R];
    #pragma unroll
    for (int r = 0; r < R; ++r) o[r] = fmaf(h[r][0], w56[0], b56);
    #pragma unroll
    for (int i = 1; i < 12; ++i) {
        const float wv = w56[i];
        #pragma unroll
        for (int r = 0; r < R; ++r) o[r] = fmaf(h[r][i], wv, o[r]);
    }

    if (full) {
        *((float4*)(out + row0)) = make_float4(o[0], o[1], o[2], o[3]);
    } else {
        #pragma unroll
        for (int r = 0; r < R; ++r)
            if ((row0 + r) < nrows) out[row0 + r] = o[r];
    }
}

extern "C" void kernel_launch(void* const* d_in, const int* in_sizes, int n_in,
                              void* d_out, int out_size, void* d_ws, size_t ws_size,
                              hipStream_t stream) {
    const float* in = (const float*)d_in[0];
    const float* W0 = (const float*)d_in[1];  const float* b0 = (const float*)d_in[2];
    const float* W1 = (const float*)d_in[3];  const float* b1 = (const float*)d_in[4];
    const float* W2 = (const float*)d_in[5];  const float* b2 = (const float*)d_in[6];
    const float* W3 = (const float*)d_in[7];  const float* b3 = (const float*)d_in[8];
    const float* W4 = (const float*)d_in[9];  const float* b4 = (const float*)d_in[10];
    const float* W5 = (const float*)d_in[11]; const float* b5 = (const float*)d_in[12];
    const float* W6 = (const float*)d_in[13]; const float* b6 = (const float*)d_in[14];
    float* out = (float*)d_out;
    float* ws = (float*)d_ws;

    // fold layers 5+6 once per call (13 floats into d_ws)
    hipLaunchKernelGGL(fuse56_kernel, dim3(1), dim3(64), 0, stream, W5, b5, W6, b6, ws);

    const int nrows = in_sizes[0] / 7;  // B*MS
    const long nthreads_total = ((long)nrows + R - 1) / R;
    const int blocks = (int)((nthreads_total + NTHREADS - 1) / NTHREADS);

    hipLaunchKernelGGL(mlp_kernel, dim3(blocks), dim3(NTHREADS), 0, stream,
                       in, W0, b0, W1, W2, W3, W4, b1, b2, b3, b4, ws,
                       out, nrows);
}